// Round 10
// baseline (474.719 us; speedup 1.0000x reference)
//
#include <hip/hip_runtime.h>

// LightGCN forward on MI355X — direct global-atomic CSR build + paired-node
// dwordx2 gather (R4-verified body).
// Inputs: d_in[0] = edge_index int32 [2, E]; d_in[1] = emb_weight f32 [N, 64].
// Output: d_out = [emb0 (N*64) | out (N*64)] f32, out = mean(emb0..emb3).
// Assumes N <= 131072 (<=256 buckets of 512). Here N=120000, E=2M, dst ~uniform.
//
// R1: LDS-scatter accum = 727 µs/layer (LDS-atomic serialization) — reverted.
// R2: paired-node dwordx2 gather: 53.3 -> 47.6 µs/gather.
// R4: 2-stage pipeline ~null; R7: uint4 col loads ~null (47.3). Gather is
//     pinned by ~137 MB L2-miss traffic/layer at ~3 TB/s (8 XCDs x 15.4 MB
//     table re-fetch) — structural for this algorithm.
// R5: 32-B quartered table REGRESSED (line over-fetch). Keep rows >= 128 B.
// R6: fusing cvt into c3 raced the e0b/slab overlay — cvt stays separate.
// R10 (this round): build rewritten — slab counting sort (c1+c3, ~105 µs of
//     serial LDS phases) replaced by: memset(deg) -> k_deg (2M global atomics
//     over 120K L2-resident counters) -> k_bsum -> c3_fin (scans, row_se/dis/
//     cursor) -> k_place (col[atomicAdd(cursor[dst])]=src; writes cluster into
//     ~68-B/node runs, L2 merges). Slab gone; ws 25.8 MB. Gather = exact R4 body.

#define DIM 64
#define BN 512          // nodes per bucket
#define BSH 9

typedef unsigned short u16;
typedef unsigned int u32;

static __device__ __forceinline__ float bf2f_lo(u32 p) { return __uint_as_float(p << 16); }
static __device__ __forceinline__ float bf2f_hi(u32 p) { return __uint_as_float(p & 0xffff0000u); }
static __device__ __forceinline__ u16 f2bf(float f) {   // round-to-nearest-even
    unsigned u = __float_as_uint(f);
    return (u16)((u + 0x7fffu + ((u >> 16) & 1u)) >> 16);
}
static __device__ __forceinline__ u32 pack2(float a, float b) {
    return (u32)f2bf(a) | ((u32)f2bf(b) << 16);
}

// deg[dst]++ over all edges. 4 edges/thread via int4; counters L2-resident.
__global__ void __launch_bounds__(256) k_deg(
        const int* __restrict__ dst, int* __restrict__ deg, int E) {
    int i = (blockIdx.x * 256 + threadIdx.x) * 4;
    if (i + 3 < E) {
        int4 d = *(const int4*)(dst + i);
        atomicAdd(&deg[d.x], 1); atomicAdd(&deg[d.y], 1);
        atomicAdd(&deg[d.z], 1); atomicAdd(&deg[d.w], 1);
    } else {
        for (; i < E; ++i) atomicAdd(&deg[dst[i]], 1);
    }
}

// Per-bucket degree sums (for the tiny redundant bucket scan in c3_fin).
__global__ void __launch_bounds__(128) k_bsum(
        const int* __restrict__ deg, int* __restrict__ btot, int N) {
    __shared__ int s[128];
    int b = blockIdx.x, t = threadIdx.x;
    int base = b << BSH;
    int sum = 0;
    for (int k = t; k < BN; k += 128) {
        int n = base + k;
        sum += (n < N) ? deg[n] : 0;
    }
    s[t] = sum; __syncthreads();
    for (int off = 64; off > 0; off >>= 1) {
        if (t < off) s[t] += s[t + off];
        __syncthreads();
    }
    if (t == 0) btot[b] = s[0];
}

// One WG per bucket: redundant 256-scan of btot -> bucket lo; 512-scan of the
// bucket's degrees -> row starts; write dis / row_se(start,end) / cursor=start.
__global__ void __launch_bounds__(512) c3_fin(
        const int* __restrict__ deg, const int* __restrict__ btot,
        int2* __restrict__ row_se, float* __restrict__ dis,
        int* __restrict__ cursor, int N, int NB) {
    __shared__ int ps[512];
    int b = blockIdx.x, tid = threadIdx.x;
    int xc = (tid < NB) ? btot[tid] : 0;
    if (tid < 256) ps[tid] = xc;
    __syncthreads();
    for (int off = 1; off < 256; off <<= 1) {
        int t = (tid >= off && tid < 256) ? ps[tid - off] : 0;
        __syncthreads();
        if (tid < 256) ps[tid] += t;
        __syncthreads();
    }
    int lo = b ? ps[b - 1] : 0;
    __syncthreads();
    int node = (b << BSH) + tid;
    int c0 = (node < N) ? deg[node] : 0;
    ps[tid] = c0;
    __syncthreads();
    for (int off = 1; off < 512; off <<= 1) {
        int t = (tid >= off) ? ps[tid - off] : 0;
        __syncthreads();
        ps[tid] += t;
        __syncthreads();
    }
    int start = lo + ps[tid] - c0;                 // exclusive
    if (node < N) {
        dis[node] = c0 ? rsqrtf((float)c0) : 0.f;
        row_se[node] = make_int2(start, start + c0);
        cursor[node] = start;
    }
}

// col[atomicAdd(cursor[dst])] = src. Reads coalesced; writes cluster into
// per-node ~68-B runs (L2 merges). Within-node order = atomic order (f32 sum
// order shifts ~1e-7, invisible under the bf16-dominated tolerance).
__global__ void __launch_bounds__(256) k_place(
        const int* __restrict__ src, const int* __restrict__ dst,
        int* __restrict__ cursor, int* __restrict__ col, int E) {
    int i = (blockIdx.x * 256 + threadIdx.x) * 4;
    if (i + 3 < E) {
        int4 s = *(const int4*)(src + i);
        int4 d = *(const int4*)(dst + i);
        col[atomicAdd(&cursor[d.x], 1)] = s.x;
        col[atomicAdd(&cursor[d.y], 1)] = s.y;
        col[atomicAdd(&cursor[d.z], 1)] = s.z;
        col[atomicAdd(&cursor[d.w], 1)] = s.w;
    } else {
        for (; i < E; ++i) col[atomicAdd(&cursor[dst[i]], 1)] = src[i];
    }
}

// e0b = bf16(dis * emb0) prescaled table; also emits the exact f32 emb0 output.
__global__ void cvt_copy(const float4* __restrict__ emb, const float* __restrict__ dis,
                         ushort4* __restrict__ e0b, float4* __restrict__ emb0_out, int n4) {
    int i = blockIdx.x * blockDim.x + threadIdx.x;
    if (i < n4) {
        float4 v = emb[i];
        float w = dis[i >> 4];
        ushort4 o;
        o.x = f2bf(w * v.x); o.y = f2bf(w * v.y);
        o.z = f2bf(w * v.z); o.w = f2bf(w * v.w);
        e0b[i] = o;
        emb0_out[i] = v;
    }
}

#define ACC4(P) { s0 += bf2f_lo((P).x); s1 += bf2f_hi((P).x);                  \
                  s2 += bf2f_lo((P).y); s3 += bf2f_hi((P).y); }

// Paired-node gather body (R4-verified, 47.0 µs @128-B table). Wave = 2 nodes
// (lane halves); subgroup g=(lane>>4)&1 handles edges j+2k+g; lane d=(lane&15)
// loads dwordx2 = dims 4d..4d+3 of the row (stride 2^SH u32). 2-stage rotation:
// issue round r's col+rows before accumulating round r-1. Tail: ONE predicated
// round, index clamped to end-1, loaded words zero-masked.
#define GATHER_BODY(CURTAB, SH)                                                \
    float s0 = 0.f, s1 = 0.f, s2 = 0.f, s3 = 0.f;                              \
    {                                                                          \
        int nfull = (end - start) >> 3;                                        \
        uint2 p0, p1, p2, p3;                                                  \
        if (nfull > 0) {                                                       \
            int j = start;                                                     \
            int a0 = col[j + g],     a1 = col[j + 2 + g];                      \
            int a2 = col[j + 4 + g], a3 = col[j + 6 + g];                      \
            p0 = *(const uint2*)((CURTAB) + (((size_t)a0) << (SH)) + 2 * d);   \
            p1 = *(const uint2*)((CURTAB) + (((size_t)a1) << (SH)) + 2 * d);   \
            p2 = *(const uint2*)((CURTAB) + (((size_t)a2) << (SH)) + 2 * d);   \
            p3 = *(const uint2*)((CURTAB) + (((size_t)a3) << (SH)) + 2 * d);   \
        }                                                                      \
        for (int r = 1; r < nfull; ++r) {                                      \
            int jn = start + 8 * r;                                            \
            int b0 = col[jn + g],     b1 = col[jn + 2 + g];                    \
            int b2 = col[jn + 4 + g], b3 = col[jn + 6 + g];                    \
            uint2 q0 = *(const uint2*)((CURTAB) + (((size_t)b0) << (SH)) + 2 * d); \
            uint2 q1 = *(const uint2*)((CURTAB) + (((size_t)b1) << (SH)) + 2 * d); \
            uint2 q2 = *(const uint2*)((CURTAB) + (((size_t)b2) << (SH)) + 2 * d); \
            uint2 q3 = *(const uint2*)((CURTAB) + (((size_t)b3) << (SH)) + 2 * d); \
            ACC4(p0) ACC4(p1) ACC4(p2) ACC4(p3)                                \
            p0 = q0; p1 = q1; p2 = q2; p3 = q3;                                \
        }                                                                      \
        if (nfull > 0) { ACC4(p0) ACC4(p1) ACC4(p2) ACC4(p3) }                 \
        int jt = start + 8 * nfull;                                            \
        if (jt < end) {                                                        \
            int endm1 = end - 1;                                               \
            _Pragma("unroll")                                                  \
            for (int k = 0; k < 4; ++k) {                                      \
                int e = jt + 2 * k + g;                                        \
                int c = col[min(e, endm1)];                                    \
                uint2 p = *(const uint2*)((CURTAB) + (((size_t)c) << (SH)) + 2 * d); \
                if (e >= end) { p.x = 0; p.y = 0; }                            \
                ACC4(p)                                                        \
            }                                                                  \
        }                                                                      \
    }                                                                          \
    s0 += __shfl_xor(s0, 16); s1 += __shfl_xor(s1, 16);                        \
    s2 += __shfl_xor(s2, 16); s3 += __shfl_xor(s3, 16);

// Mid layer: next[node] = bf16(w^2 * sum of prescaled neighbor rows).
// INSH/OUTSH = log2 row stride in u32 (5 = 128-B table, 6 = parked in 256-B out rows).
template<int INSH, int OUTSH>
__global__ void __launch_bounds__(256) gather_mid(
        const int2* __restrict__ row_se, const int* __restrict__ col,
        const float* __restrict__ dis, const u32* __restrict__ cur,
        u32* __restrict__ next, int N) {
    int t = blockIdx.x * blockDim.x + threadIdx.x;
    int pair = t >> 6, lane = t & 63;
    if (2 * pair >= N) return;
    int node = 2 * pair + (lane >> 5);
    int g = (lane >> 4) & 1, d = lane & 15;
    bool valid = node < N;
    int2 se = valid ? row_se[node] : make_int2(0, 0);
    int start = se.x, end = se.y;
    GATHER_BODY(cur, INSH)
    if (valid && g == 0) {
        float w = dis[node], ww = w * w;
        uint2 o;
        o.x = pack2(ww * s0, ww * s1);
        o.y = pack2(ww * s2, ww * s3);
        *(uint2*)(next + (((size_t)node) << OUTSH) + 2 * d) = o;
    }
}

// Final gather (layer 3) fused with the mean epilogue:
// out = 0.25 * (e0 + (e1b + e2b)/w + e3),  e3 = w * sum(prescaled e2b neighbors).
// e1b is parked in the first 128 B of each 256-B out row (stride 64 u32); each
// wave's q1 loads precede its dependent out stores in program order (same-wave
// load-before-store — R7-verified pattern). e1b/out alias: no __restrict__.
__global__ void __launch_bounds__(256) gather_final(
        const int2* __restrict__ row_se, const int* __restrict__ col,
        const float* __restrict__ dis, const u32* __restrict__ cur /* e2b */,
        const u32* e1b, const float* __restrict__ emb0,
        float* out, int N) {
    int t = blockIdx.x * blockDim.x + threadIdx.x;
    int pair = t >> 6, lane = t & 63;
    if (2 * pair >= N) return;
    int node = 2 * pair + (lane >> 5);
    int g = (lane >> 4) & 1, d = lane & 15;
    bool valid = node < N;
    int2 se = valid ? row_se[node] : make_int2(0, 0);
    int start = se.x, end = se.y;
    GATHER_BODY(cur, 5)
    if (valid && g == 0) {
        float w = dis[node];
        float inv = (w > 0.f) ? 1.0f / w : 0.f;
        uint2 q1 = *(const uint2*)(e1b + ((size_t)node << 6) + 2 * d);
        uint2 q2 = *(const uint2*)(cur + ((size_t)node << 5) + 2 * d);
        size_t fo = (size_t)node * 64 + 4 * d;             // float units
        float4 e0 = *(const float4*)(emb0 + fo);
        float4 r;
        r.x = 0.25f * (e0.x + (bf2f_lo(q1.x) + bf2f_lo(q2.x)) * inv + w * s0);
        r.y = 0.25f * (e0.y + (bf2f_hi(q1.x) + bf2f_hi(q2.x)) * inv + w * s1);
        r.z = 0.25f * (e0.z + (bf2f_lo(q1.y) + bf2f_lo(q2.y)) * inv + w * s2);
        r.w = 0.25f * (e0.w + (bf2f_hi(q1.y) + bf2f_hi(q2.y)) * inv + w * s3);
        *(float4*)(out + fo) = r;
    }
}

extern "C" void kernel_launch(void* const* d_in, const int* in_sizes, int n_in,
                              void* d_out, int out_size, void* d_ws, size_t ws_size,
                              hipStream_t stream) {
    const int*   edge  = (const int*)d_in[0];
    const float* emb_w = (const float*)d_in[1];
    const int E = in_sizes[0] / 2;
    const int N = in_sizes[1] / DIM;
    const int* src = edge;         // edge_index[0]
    const int* dst = edge + E;     // edge_index[1]

    const int NB = (N + BN - 1) >> BSH;           // <= 256

    float* out_base = (float*)d_out;
    float* emb0_out = out_base;                       // first half of d_out
    float* acc      = out_base + (size_t)N * DIM;     // second half -> out
    u32*   e1b      = (u32*)acc;                      // e1b row n = first 128 B of out row n

    // ws: [dis: N][row_se: N int2][deg: N][cursor: N][btot: 256][col: E]
    //     [e0b: N*32 u32] — total ~25.8 MB (< 32.2 MB proven safe). No slab.
    float* dis    = (float*)d_ws;
    int2*  row_se = (int2*)(dis + ((N + 3) & ~3));
    int*   deg    = (int*)(row_se + N);
    int*   cursor = deg + ((N + 3) & ~3);
    int*   btot   = cursor + ((N + 3) & ~3);
    int*   col    = btot + 256;
    u32*   e0b    = (u32*)(col + ((E + 3) & ~3));

    const int BLK   = 256;
    const int n4    = N * DIM / 4;
    const int g4    = (n4 + BLK - 1) / BLK;
    const int gE    = (E + BLK * 4 - 1) / (BLK * 4);  // 4 edges/thread
    const int PAIRS = (N + 1) / 2;                    // 2 nodes per 64-lane wave
    const int gW    = (PAIRS * 64 + BLK - 1) / BLK;

    // --- CSR build: global-atomic counting sort (no slab) ---
    hipMemsetAsync(deg, 0, (size_t)N * sizeof(int), stream);
    k_deg<<<gE, BLK, 0, stream>>>(dst, deg, E);
    k_bsum<<<NB, 128, 0, stream>>>(deg, btot, N);
    c3_fin<<<NB, 512, 0, stream>>>(deg, btot, row_se, dis, cursor, N, NB);
    k_place<<<gE, BLK, 0, stream>>>(src, dst, cursor, col, E);

    // Prescaled bf16 table + exact emb0 output.
    cvt_copy<<<g4, BLK, 0, stream>>>((const float4*)emb_w, dis,
                                     (ushort4*)e0b, (float4*)emb0_out, n4);

    // Layer 1: e1b = bf16(w*e1), parked in out rows (stride 64 u32)
    gather_mid<5, 6><<<gW, BLK, 0, stream>>>(row_se, col, dis, e0b, e1b, N);
    // Layer 2: e2b -> e0b region (e0b dead), reading parked e1b (stride 64)
    gather_mid<6, 5><<<gW, BLK, 0, stream>>>(row_se, col, dis, e1b, e0b, N);
    // Layer 3 + mean epilogue (overwrites parked e1b rows with final out)
    gather_final<<<gW, BLK, 0, stream>>>(row_se, col, dis, e0b, e1b,
                                         emb_w, acc, N);
}

// Round 11
// 252.891 us; speedup vs baseline: 1.8772x; 1.8772x over previous
//
#include <hip/hip_runtime.h>

// LightGCN forward on MI355X — slab-bucketed CSR build + paired-node dwordx2 gather
// with explicit 2-stage software pipeline. (R4-verified structure, 1024-thread build.)
// Inputs: d_in[0] = edge_index int32 [2, E]; d_in[1] = emb_weight f32 [N, 64].
// Output: d_out = [emb0 (N*64) | out (N*64)] f32, out = mean(emb0..emb3).
// Assumes N <= 131072 (<=256 buckets). Here N=120000, E=2M, dst ~uniform.
//
// R1: LDS-scatter accum = 727 µs/layer (LDS-atomic serialization) — reverted.
// R2: paired-node dwordx2 gather: 53.3 -> 47.6 µs/gather.
// R4: 2-stage pipeline ~null; R7: uint4 col loads ~null. Gather pinned by
//     ~137 MB L2-miss traffic/layer at ~3 TB/s fabric — structural.
// R5: 32-B quartered table REGRESSED (line over-fetch). Keep rows >= 128 B.
// R6: fusing cvt into c3 raced the e0b/slab overlay — cvt stays separate.
// R10: global-atomic build REGRESSED (k_place 178 µs): scattered 4-B col
//     stores cost full 64-B lines (WRITE 131 MB) and atomic-return chains
//     serialize. Slab staging (coalesced writes) is the right build.
// R11 (this round): exact R4 kernel, but c1_scatter/c3_build at 1024 threads
//     (strided phases 8->4 and 34->17 rounds; scans guarded; same LDS layout).

#define DIM 64
#define BN 512          // nodes per bucket
#define BSH 9
#define CHUNK 4096      // edges per scatter workgroup (2 WGs/CU overlap)

typedef unsigned short u16;
typedef unsigned int u32;

static __device__ __forceinline__ float bf2f_lo(u32 p) { return __uint_as_float(p << 16); }
static __device__ __forceinline__ float bf2f_hi(u32 p) { return __uint_as_float(p & 0xffff0000u); }
static __device__ __forceinline__ u16 f2bf(float f) {   // round-to-nearest-even
    unsigned u = __float_as_uint(f);
    return (u16)((u + 0x7fffu + ((u >> 16) & 1u)) >> 16);
}
static __device__ __forceinline__ u32 pack2(float a, float b) {
    return (u32)f2bf(a) | ((u32)f2bf(b) << 16);
}

__global__ void zero_cur(int* __restrict__ cursor) { cursor[threadIdx.x] = 0; }

// Per-chunk LDS counting-sort by bucket; slab space reserved with one global
// atomicAdd per (chunk,bucket). 1024 threads: 4 rounds per strided phase.
__global__ void __launch_bounds__(1024) c1_scatter(
        const int* __restrict__ src, const int* __restrict__ dst,
        int* __restrict__ cursor, u32* __restrict__ slab, int E, int CAP) {
    __shared__ u32 buf[CHUNK];
    __shared__ unsigned char bb[CHUNK];
    __shared__ int posb[256], startb[256], gbase[256];
    int w = blockIdx.x, tid = threadIdx.x;
    int lo = w * CHUNK, hi = min(lo + CHUNK, E);
    if (tid < 256) posb[tid] = 0;
    __syncthreads();
    for (int i = lo + tid; i < hi; i += 1024) atomicAdd(&posb[dst[i] >> BSH], 1);
    __syncthreads();
    int x = 0;
    if (tid < 256) {
        x = posb[tid];
        gbase[tid] = x ? atomicAdd(cursor + tid, x) : 0;   // slab reservation
    }
    __syncthreads();
    for (int off = 1; off < 256; off <<= 1) {              // in-place scan of posb
        int t = (tid >= off && tid < 256) ? posb[tid - off] : 0;
        __syncthreads();
        if (tid < 256) posb[tid] += t;
        __syncthreads();
    }
    if (tid < 256) startb[tid] = posb[tid] - x;
    __syncthreads();
    if (tid < 256) posb[tid] = startb[tid];                // placement cursor
    __syncthreads();
    for (int i = lo + tid; i < hi; i += 1024) {
        int d = dst[i], b = d >> BSH;
        int q = atomicAdd(&posb[b], 1);
        buf[q] = ((u32)src[i] << BSH) | (u32)(d & (BN - 1));
        bb[q] = (unsigned char)b;
    }
    __syncthreads();
    int n = hi - lo;
    for (int q = tid; q < n; q += 1024) {                  // coalesced bucket-run writes
        int b = bb[q];
        slab[(size_t)b * CAP + gbase[b] + (q - startb[b])] = buf[q];
    }
}

// One WG per bucket: bucket_lo scan -> node-hist -> scan -> dis/row_se -> col.
// 1024 threads: hist/placement passes go 34 -> 17 strided rounds per bucket.
__global__ void __launch_bounds__(1024) c3_build(
        const u32* __restrict__ slab, const int* __restrict__ cursor,
        int* __restrict__ col, int2* __restrict__ row_se, float* __restrict__ dis,
        int N, int CAP, int NB) {
    __shared__ int cur[BN];
    __shared__ int ps[BN];
    int b = blockIdx.x, tid = threadIdx.x;
    // exclusive prefix of bucket counts -> this bucket's lo (first 256 threads)
    int xc = (tid < NB) ? cursor[tid] : 0;
    if (tid < 256) ps[tid] = xc;
    __syncthreads();
    for (int off = 1; off < 256; off <<= 1) {
        int t = (tid >= off && tid < 256) ? ps[tid - off] : 0;
        __syncthreads();
        if (tid < 256) ps[tid] += t;
        __syncthreads();
    }
    int lo  = b ? ps[b - 1] : 0;
    int cnt = cursor[b];
    __syncthreads();

    int nodeBase = b << BSH;
    int nLoc = min(BN, N - nodeBase);
    const u32* sp = slab + (size_t)b * CAP;
    if (tid < BN) cur[tid] = 0;                            // 512 nodes
    __syncthreads();
    for (int i = tid; i < cnt; i += 1024) atomicAdd(&cur[sp[i] & (BN - 1)], 1);
    __syncthreads();
    int c0 = (tid < BN) ? cur[tid] : 0;
    if (tid < BN) ps[tid] = c0;
    __syncthreads();
    for (int off = 1; off < BN; off <<= 1) {               // scan of node counts
        int t = (tid >= off && tid < BN) ? ps[tid - off] : 0;
        __syncthreads();
        if (tid < BN) ps[tid] += t;
        __syncthreads();
    }
    if (tid < BN) {
        int base = ps[tid] - c0;                           // exclusive
        cur[tid] = base;                                   // placement cursor
        if (tid < nLoc) {
            dis[nodeBase + tid] = c0 ? rsqrtf((float)c0) : 0.f;
            row_se[nodeBase + tid] = make_int2(lo + base, lo + base + c0);
        }
    }
    __syncthreads();
    for (int i = tid; i < cnt; i += 1024) {
        u32 v = sp[i];
        int q = atomicAdd(&cur[v & (BN - 1)], 1);
        col[lo + q] = (int)(v >> BSH);       // confined to this WG's region
    }
}

// e0b = bf16(dis * emb0) prescaled table; also emits the exact f32 emb0 output.
// SEPARATE kernel (after c3_build retires) — slab/e0b overlay only then safe (R6).
__global__ void cvt_copy(const float4* __restrict__ emb, const float* __restrict__ dis,
                         ushort4* __restrict__ e0b, float4* __restrict__ emb0_out, int n4) {
    int i = blockIdx.x * blockDim.x + threadIdx.x;
    if (i < n4) {
        float4 v = emb[i];
        float w = dis[i >> 4];
        ushort4 o;
        o.x = f2bf(w * v.x); o.y = f2bf(w * v.y);
        o.z = f2bf(w * v.z); o.w = f2bf(w * v.w);
        e0b[i] = o;
        emb0_out[i] = v;
    }
}

#define ACC4(P) { s0 += bf2f_lo((P).x); s1 += bf2f_hi((P).x);                  \
                  s2 += bf2f_lo((P).y); s3 += bf2f_hi((P).y); }

// Paired-node gather body (R4-verified). Wave = 2 nodes (lane halves); subgroup
// g=(lane>>4)&1 handles edges j+2k+g; lane d=(lane&15) loads dwordx2 = dims
// 4d..4d+3 of the 128-B prescaled row. 2-stage rotation: issue round r's
// col+rows before accumulating round r-1. Tail: ONE predicated round, index
// clamped to end-1, loaded words zero-masked. Reduce across g via shfl_xor(16).
#define GATHER_BODY(CURTAB)                                                    \
    float s0 = 0.f, s1 = 0.f, s2 = 0.f, s3 = 0.f;                              \
    {                                                                          \
        int nfull = (end - start) >> 3;                                        \
        uint2 p0, p1, p2, p3;                                                  \
        if (nfull > 0) {                                                       \
            int j = start;                                                     \
            int a0 = col[j + g],     a1 = col[j + 2 + g];                      \
            int a2 = col[j + 4 + g], a3 = col[j + 6 + g];                      \
            p0 = *(const uint2*)((CURTAB) + (((size_t)a0) << 5) + 2 * d);      \
            p1 = *(const uint2*)((CURTAB) + (((size_t)a1) << 5) + 2 * d);      \
            p2 = *(const uint2*)((CURTAB) + (((size_t)a2) << 5) + 2 * d);      \
            p3 = *(const uint2*)((CURTAB) + (((size_t)a3) << 5) + 2 * d);      \
        }                                                                      \
        for (int r = 1; r < nfull; ++r) {                                      \
            int jn = start + 8 * r;                                            \
            int b0 = col[jn + g],     b1 = col[jn + 2 + g];                    \
            int b2 = col[jn + 4 + g], b3 = col[jn + 6 + g];                    \
            uint2 q0 = *(const uint2*)((CURTAB) + (((size_t)b0) << 5) + 2 * d);\
            uint2 q1 = *(const uint2*)((CURTAB) + (((size_t)b1) << 5) + 2 * d);\
            uint2 q2 = *(const uint2*)((CURTAB) + (((size_t)b2) << 5) + 2 * d);\
            uint2 q3 = *(const uint2*)((CURTAB) + (((size_t)b3) << 5) + 2 * d);\
            ACC4(p0) ACC4(p1) ACC4(p2) ACC4(p3)                                \
            p0 = q0; p1 = q1; p2 = q2; p3 = q3;                                \
        }                                                                      \
        if (nfull > 0) { ACC4(p0) ACC4(p1) ACC4(p2) ACC4(p3) }                 \
        int jt = start + 8 * nfull;                                            \
        if (jt < end) {                                                        \
            int endm1 = end - 1;                                               \
            _Pragma("unroll")                                                  \
            for (int k = 0; k < 4; ++k) {                                      \
                int e = jt + 2 * k + g;                                        \
                int c = col[min(e, endm1)];                                    \
                uint2 p = *(const uint2*)((CURTAB) + (((size_t)c) << 5) + 2 * d); \
                if (e >= end) { p.x = 0; p.y = 0; }                            \
                ACC4(p)                                                        \
            }                                                                  \
        }                                                                      \
    }                                                                          \
    s0 += __shfl_xor(s0, 16); s1 += __shfl_xor(s1, 16);                        \
    s2 += __shfl_xor(s2, 16); s3 += __shfl_xor(s3, 16);

// cur is the PRESCALED table (dis ⊙ e). Writes next = bf16(w*e) only.
__global__ void __launch_bounds__(256) gather_mid(
        const int2* __restrict__ row_se, const int* __restrict__ col,
        const float* __restrict__ dis, const u32* __restrict__ cur,
        u32* __restrict__ next, int N) {
    int t = blockIdx.x * blockDim.x + threadIdx.x;
    int pair = t >> 6, lane = t & 63;
    if (2 * pair >= N) return;
    int node = 2 * pair + (lane >> 5);
    int g = (lane >> 4) & 1, d = lane & 15;
    bool valid = node < N;
    int2 se = valid ? row_se[node] : make_int2(0, 0);
    int start = se.x, end = se.y;
    GATHER_BODY(cur)
    if (valid && g == 0) {
        float w = dis[node], ww = w * w;
        uint2 o;
        o.x = pack2(ww * s0, ww * s1);
        o.y = pack2(ww * s2, ww * s3);
        *(uint2*)(next + (((size_t)node) << 5) + 2 * d) = o;
    }
}

// Final gather (layer 3) fused with the mean epilogue:
// out = 0.25 * (e0 + (e1b + e2b)/w + e3),  e3 = w * sum(prescaled e2b neighbors).
__global__ void __launch_bounds__(256) gather_final(
        const int2* __restrict__ row_se, const int* __restrict__ col,
        const float* __restrict__ dis, const u32* __restrict__ cur /* e2b */,
        const u32* __restrict__ e1b, const float* __restrict__ emb0,
        float* __restrict__ out, int N) {
    int t = blockIdx.x * blockDim.x + threadIdx.x;
    int pair = t >> 6, lane = t & 63;
    if (2 * pair >= N) return;
    int node = 2 * pair + (lane >> 5);
    int g = (lane >> 4) & 1, d = lane & 15;
    bool valid = node < N;
    int2 se = valid ? row_se[node] : make_int2(0, 0);
    int start = se.x, end = se.y;
    GATHER_BODY(cur)
    if (valid && g == 0) {
        float w = dis[node];
        float inv = (w > 0.f) ? 1.0f / w : 0.f;
        size_t idx = (((size_t)node) << 5) + 2 * d;        // u32 units
        uint2 q1 = *(const uint2*)(e1b + idx);
        uint2 q2 = *(const uint2*)(cur + idx);
        float4 e0 = *(const float4*)(emb0 + 2 * idx);      // node*64 + 4d floats
        float4 r;
        r.x = 0.25f * (e0.x + (bf2f_lo(q1.x) + bf2f_lo(q2.x)) * inv + w * s0);
        r.y = 0.25f * (e0.y + (bf2f_hi(q1.x) + bf2f_hi(q2.x)) * inv + w * s1);
        r.z = 0.25f * (e0.z + (bf2f_lo(q1.y) + bf2f_lo(q2.y)) * inv + w * s2);
        r.w = 0.25f * (e0.w + (bf2f_hi(q1.y) + bf2f_hi(q2.y)) * inv + w * s3);
        *(float4*)(out + 2 * idx) = r;
    }
}

extern "C" void kernel_launch(void* const* d_in, const int* in_sizes, int n_in,
                              void* d_out, int out_size, void* d_ws, size_t ws_size,
                              hipStream_t stream) {
    const int*   edge  = (const int*)d_in[0];
    const float* emb_w = (const float*)d_in[1];
    const int E = in_sizes[0] / 2;
    const int N = in_sizes[1] / DIM;
    const int* src = edge;         // edge_index[0]
    const int* dst = edge + E;     // edge_index[1]

    const int NB  = (N + BN - 1) >> BSH;          // <= 256
    const int nCh = (E + CHUNK - 1) / CHUNK;
    const int CAP = (E / (NB > 0 ? NB : 1)) * 2;  // 2x mean bucket load (uniform dst)

    float* out_base = (float*)d_out;
    float* emb0_out = out_base;                       // first half of d_out
    float* acc      = out_base + (size_t)N * DIM;     // second half -> out

    // ws: [dis: N][row_se: N int2][cursor: 256][col: E]
    //     [zone: slab (NB*CAP u32) overlaid later by e0b|e1b (2 * N*64 u16)]
    float* dis       = (float*)d_ws;
    int2*  row_se    = (int2*)(dis + ((N + 1) & ~1));
    int*   cursor    = (int*)(row_se + N);
    int*   col       = cursor + 256;
    u32*   slab      = (u32*)(col + E);
    u16*   e0b       = (u16*)slab;                    // overlays slab (dead after c3)
    u16*   e1b       = e0b + (size_t)N * DIM;

    const int n4    = N * DIM / 4;
    const int BLK   = 256;
    const int g4    = (n4 + BLK - 1) / BLK;
    const int PAIRS = (N + 1) / 2;                    // 2 nodes per 64-lane wave
    const int gW    = (PAIRS * 64 + BLK - 1) / BLK;

    // --- CSR build ---
    zero_cur<<<1, 256, 0, stream>>>(cursor);
    c1_scatter<<<nCh, 1024, 0, stream>>>(src, dst, cursor, slab, E, CAP);
    c3_build<<<NB, 1024, 0, stream>>>(slab, cursor, col, row_se, dis, N, CAP, NB);

    // Prescaled bf16 table + exact emb0 output (slab dead now).
    cvt_copy<<<g4, BLK, 0, stream>>>((const float4*)emb_w, dis,
                                     (ushort4*)e0b, (float4*)emb0_out, n4);

    // Layer 1: e1b = bf16(w*e1)
    gather_mid<<<gW, BLK, 0, stream>>>(row_se, col, dis, (const u32*)e0b, (u32*)e1b, N);
    // Layer 2: e2b = bf16(w*e2)  (e0b region reused as output)
    gather_mid<<<gW, BLK, 0, stream>>>(row_se, col, dis, (const u32*)e1b, (u32*)e0b, N);
    // Layer 3 + mean epilogue
    gather_final<<<gW, BLK, 0, stream>>>(row_se, col, dis, (const u32*)e0b, (const u32*)e1b,
                                         emb_w, acc, N);
}

// Round 12
// 247.498 us; speedup vs baseline: 1.9181x; 1.0218x over previous
//
#include <hip/hip_runtime.h>

// LightGCN forward on MI355X — slab-bucketed CSR build (register-staged, rank-trick)
// + paired-node dwordx2 gather with explicit 2-stage software pipeline.
// Inputs: d_in[0] = edge_index int32 [2, E]; d_in[1] = emb_weight f32 [N, 64].
// Output: d_out = [emb0 (N*64) | out (N*64)] f32, out = mean(emb0..emb3).
// Assumes N <= 131072 (<=256 buckets). Here N=120000, E=2M, dst ~uniform.
//
// R1: LDS-scatter accum = 727 µs/layer (LDS-atomic serialization) — reverted.
// R2: paired-node dwordx2 gather: 53.3 -> 47.6 µs/gather.
// R4/R7: pipeline + uint4 col loads ~null. Gather FETCH 137 MB = COMPULSORY
//     floor (8 XCDs x 15.4 MB table, ~once each, + col 8 MB) at ~2.9 TB/s
//     random-access fabric rate — structural for this algorithm.
// R5: 32-B quartered table REGRESSED (line over-fetch). Keep rows >= 128 B.
// R6: fusing cvt into c3 raced the e0b/slab overlay — cvt stays separate.
// R10: global-atomic build REGRESSED (scattered 4-B stores = full-line writes,
//     atomic-return chains serialize). Slab staging is the right build.
// R11: 1024-thread build: 262 -> 252.9. Build is PASS-bound, not round-bound.
// R12 (this round): cut passes — c1 reads its 4 edges once into registers
//     (feeds hist AND placement; deletes a full dst pass); c3 keeps each edge's
//     histogram rank in registers (EPT=20 unrolled) so placement needs no
//     second slab read and no second atomic pass; zero_cur -> hipMemsetAsync.

#define DIM 64
#define BN 512          // nodes per bucket
#define BSH 9
#define CHUNK 4096      // edges per scatter workgroup (2 WGs/CU overlap)
#define EPT 20          // c3 max edges/thread: ceil(CAP/1024); CAP<=17020 here

typedef unsigned short u16;
typedef unsigned int u32;

static __device__ __forceinline__ float bf2f_lo(u32 p) { return __uint_as_float(p << 16); }
static __device__ __forceinline__ float bf2f_hi(u32 p) { return __uint_as_float(p & 0xffff0000u); }
static __device__ __forceinline__ u16 f2bf(float f) {   // round-to-nearest-even
    unsigned u = __float_as_uint(f);
    return (u16)((u + 0x7fffu + ((u >> 16) & 1u)) >> 16);
}
static __device__ __forceinline__ u32 pack2(float a, float b) {
    return (u32)f2bf(a) | ((u32)f2bf(b) << 16);
}

// Per-chunk LDS counting-sort by bucket; slab space reserved with one global
// atomicAdd per (chunk,bucket). Register-staged: each thread's 4 edges are
// loaded ONCE (int4) before the first barrier and feed both hist & placement.
__global__ void __launch_bounds__(1024) c1_scatter(
        const int* __restrict__ src, const int* __restrict__ dst,
        int* __restrict__ cursor, u32* __restrict__ slab, int E, int CAP) {
    __shared__ u32 buf[CHUNK];
    __shared__ unsigned char bb[CHUNK];
    __shared__ int posb[256], startb[256], gbase[256];
    int w = blockIdx.x, tid = threadIdx.x;
    int lo = w * CHUNK, hi = min(lo + CHUNK, E);
    int i0 = lo + tid * 4;
    int nE = min(4, max(0, hi - i0));
    int sv[4], dv[4];
    if (nE == 4) {                                         // 16-B aligned (i0 % 4 == 0)
        int4 s4 = *(const int4*)(src + i0);
        int4 d4 = *(const int4*)(dst + i0);
        sv[0] = s4.x; sv[1] = s4.y; sv[2] = s4.z; sv[3] = s4.w;
        dv[0] = d4.x; dv[1] = d4.y; dv[2] = d4.z; dv[3] = d4.w;
    } else {
#pragma unroll
        for (int k = 0; k < 4; ++k) {
            sv[k] = 0; dv[k] = 0;
            if (k < nE) { sv[k] = src[i0 + k]; dv[k] = dst[i0 + k]; }
        }
    }
    if (tid < 256) posb[tid] = 0;
    __syncthreads();
#pragma unroll
    for (int k = 0; k < 4; ++k)
        if (k < nE) atomicAdd(&posb[dv[k] >> BSH], 1);
    __syncthreads();
    int x = 0;
    if (tid < 256) {
        x = posb[tid];
        gbase[tid] = x ? atomicAdd(cursor + tid, x) : 0;   // slab reservation
    }
    __syncthreads();
    for (int off = 1; off < 256; off <<= 1) {              // in-place scan of posb
        int t = (tid >= off && tid < 256) ? posb[tid - off] : 0;
        __syncthreads();
        if (tid < 256) posb[tid] += t;
        __syncthreads();
    }
    if (tid < 256) startb[tid] = posb[tid] - x;
    __syncthreads();
    if (tid < 256) posb[tid] = startb[tid];                // placement cursor
    __syncthreads();
#pragma unroll
    for (int k = 0; k < 4; ++k)
        if (k < nE) {
            int d = dv[k], b = d >> BSH;
            int q = atomicAdd(&posb[b], 1);
            buf[q] = ((u32)sv[k] << BSH) | (u32)(d & (BN - 1));
            bb[q] = (unsigned char)b;
        }
    __syncthreads();
    int n = hi - lo;
    for (int q = tid; q < n; q += 1024) {                  // coalesced bucket-run writes
        int b = bb[q];
        slab[(size_t)b * CAP + gbase[b] + (q - startb[b])] = buf[q];
    }
}

// One WG per bucket. Rank trick: the histogram atomicAdd RETURNS each edge's
// rank within its node; (slab word, rank) stay in statically-indexed register
// arrays (EPT unrolled, predicated), so placement is one atomic-free pass:
// col[lo + base[node] + rank] = src. No second slab read.
__global__ void __launch_bounds__(1024) c3_build(
        const u32* __restrict__ slab, const int* __restrict__ cursor,
        int* __restrict__ col, int2* __restrict__ row_se, float* __restrict__ dis,
        int N, int CAP, int NB) {
    __shared__ int cur[BN];
    __shared__ int ps[BN];
    int b = blockIdx.x, tid = threadIdx.x;
    // exclusive prefix of bucket counts -> this bucket's lo (first 256 threads)
    int xc = (tid < NB) ? cursor[tid] : 0;
    if (tid < 256) ps[tid] = xc;
    __syncthreads();
    for (int off = 1; off < 256; off <<= 1) {
        int t = (tid >= off && tid < 256) ? ps[tid - off] : 0;
        __syncthreads();
        if (tid < 256) ps[tid] += t;
        __syncthreads();
    }
    int lo  = b ? ps[b - 1] : 0;
    int cnt = cursor[b];
    __syncthreads();

    int nodeBase = b << BSH;
    int nLoc = min(BN, N - nodeBase);
    const u32* sp = slab + (size_t)b * CAP;
    if (tid < BN) cur[tid] = 0;                            // node histogram
    __syncthreads();
    u32 ew[EPT];                                           // slab words (static idx)
    u32 rk[EPT];                                           // ranks from hist atomics
#pragma unroll
    for (int k = 0; k < EPT; ++k) {
        int i = tid + (k << 10);
        ew[k] = 0; rk[k] = 0;
        if (i < cnt) {
            u32 v = sp[i];
            ew[k] = v;
            rk[k] = atomicAdd(&cur[v & (BN - 1)], 1);
        }
    }
    __syncthreads();
    int c0 = (tid < BN) ? cur[tid] : 0;
    if (tid < BN) ps[tid] = c0;
    __syncthreads();
    for (int off = 1; off < BN; off <<= 1) {               // scan of node counts
        int t = (tid >= off && tid < BN) ? ps[tid - off] : 0;
        __syncthreads();
        if (tid < BN) ps[tid] += t;
        __syncthreads();
    }
    if (tid < BN) {
        int base = ps[tid] - c0;                           // exclusive
        cur[tid] = base;                                   // node base (no atomics now)
        if (tid < nLoc) {
            dis[nodeBase + tid] = c0 ? rsqrtf((float)c0) : 0.f;
            row_se[nodeBase + tid] = make_int2(lo + base, lo + base + c0);
        }
    }
    __syncthreads();
#pragma unroll
    for (int k = 0; k < EPT; ++k) {
        int i = tid + (k << 10);
        if (i < cnt) {
            u32 v = ew[k];
            col[lo + cur[v & (BN - 1)] + (int)rk[k]] = (int)(v >> BSH);
        }
    }
}

// e0b = bf16(dis * emb0) prescaled table; also emits the exact f32 emb0 output.
// SEPARATE kernel (after c3_build retires) — slab/e0b overlay only then safe (R6).
__global__ void cvt_copy(const float4* __restrict__ emb, const float* __restrict__ dis,
                         ushort4* __restrict__ e0b, float4* __restrict__ emb0_out, int n4) {
    int i = blockIdx.x * blockDim.x + threadIdx.x;
    if (i < n4) {
        float4 v = emb[i];
        float w = dis[i >> 4];
        ushort4 o;
        o.x = f2bf(w * v.x); o.y = f2bf(w * v.y);
        o.z = f2bf(w * v.z); o.w = f2bf(w * v.w);
        e0b[i] = o;
        emb0_out[i] = v;
    }
}

#define ACC4(P) { s0 += bf2f_lo((P).x); s1 += bf2f_hi((P).x);                  \
                  s2 += bf2f_lo((P).y); s3 += bf2f_hi((P).y); }

// Paired-node gather body (R4-verified). Wave = 2 nodes (lane halves); subgroup
// g=(lane>>4)&1 handles edges j+2k+g; lane d=(lane&15) loads dwordx2 = dims
// 4d..4d+3 of the 128-B prescaled row. 2-stage rotation: issue round r's
// col+rows before accumulating round r-1. Tail: ONE predicated round, index
// clamped to end-1, loaded words zero-masked. Reduce across g via shfl_xor(16).
#define GATHER_BODY(CURTAB)                                                    \
    float s0 = 0.f, s1 = 0.f, s2 = 0.f, s3 = 0.f;                              \
    {                                                                          \
        int nfull = (end - start) >> 3;                                        \
        uint2 p0, p1, p2, p3;                                                  \
        if (nfull > 0) {                                                       \
            int j = start;                                                     \
            int a0 = col[j + g],     a1 = col[j + 2 + g];                      \
            int a2 = col[j + 4 + g], a3 = col[j + 6 + g];                      \
            p0 = *(const uint2*)((CURTAB) + (((size_t)a0) << 5) + 2 * d);      \
            p1 = *(const uint2*)((CURTAB) + (((size_t)a1) << 5) + 2 * d);      \
            p2 = *(const uint2*)((CURTAB) + (((size_t)a2) << 5) + 2 * d);      \
            p3 = *(const uint2*)((CURTAB) + (((size_t)a3) << 5) + 2 * d);      \
        }                                                                      \
        for (int r = 1; r < nfull; ++r) {                                      \
            int jn = start + 8 * r;                                            \
            int b0 = col[jn + g],     b1 = col[jn + 2 + g];                    \
            int b2 = col[jn + 4 + g], b3 = col[jn + 6 + g];                    \
            uint2 q0 = *(const uint2*)((CURTAB) + (((size_t)b0) << 5) + 2 * d);\
            uint2 q1 = *(const uint2*)((CURTAB) + (((size_t)b1) << 5) + 2 * d);\
            uint2 q2 = *(const uint2*)((CURTAB) + (((size_t)b2) << 5) + 2 * d);\
            uint2 q3 = *(const uint2*)((CURTAB) + (((size_t)b3) << 5) + 2 * d);\
            ACC4(p0) ACC4(p1) ACC4(p2) ACC4(p3)                                \
            p0 = q0; p1 = q1; p2 = q2; p3 = q3;                                \
        }                                                                      \
        if (nfull > 0) { ACC4(p0) ACC4(p1) ACC4(p2) ACC4(p3) }                 \
        int jt = start + 8 * nfull;                                            \
        if (jt < end) {                                                        \
            int endm1 = end - 1;                                               \
            _Pragma("unroll")                                                  \
            for (int k = 0; k < 4; ++k) {                                      \
                int e = jt + 2 * k + g;                                        \
                int c = col[min(e, endm1)];                                    \
                uint2 p = *(const uint2*)((CURTAB) + (((size_t)c) << 5) + 2 * d); \
                if (e >= end) { p.x = 0; p.y = 0; }                            \
                ACC4(p)                                                        \
            }                                                                  \
        }                                                                      \
    }                                                                          \
    s0 += __shfl_xor(s0, 16); s1 += __shfl_xor(s1, 16);                        \
    s2 += __shfl_xor(s2, 16); s3 += __shfl_xor(s3, 16);

// cur is the PRESCALED table (dis ⊙ e). Writes next = bf16(w*e) only.
__global__ void __launch_bounds__(256) gather_mid(
        const int2* __restrict__ row_se, const int* __restrict__ col,
        const float* __restrict__ dis, const u32* __restrict__ cur,
        u32* __restrict__ next, int N) {
    int t = blockIdx.x * blockDim.x + threadIdx.x;
    int pair = t >> 6, lane = t & 63;
    if (2 * pair >= N) return;
    int node = 2 * pair + (lane >> 5);
    int g = (lane >> 4) & 1, d = lane & 15;
    bool valid = node < N;
    int2 se = valid ? row_se[node] : make_int2(0, 0);
    int start = se.x, end = se.y;
    GATHER_BODY(cur)
    if (valid && g == 0) {
        float w = dis[node], ww = w * w;
        uint2 o;
        o.x = pack2(ww * s0, ww * s1);
        o.y = pack2(ww * s2, ww * s3);
        *(uint2*)(next + (((size_t)node) << 5) + 2 * d) = o;
    }
}

// Final gather (layer 3) fused with the mean epilogue:
// out = 0.25 * (e0 + (e1b + e2b)/w + e3),  e3 = w * sum(prescaled e2b neighbors).
__global__ void __launch_bounds__(256) gather_final(
        const int2* __restrict__ row_se, const int* __restrict__ col,
        const float* __restrict__ dis, const u32* __restrict__ cur /* e2b */,
        const u32* __restrict__ e1b, const float* __restrict__ emb0,
        float* __restrict__ out, int N) {
    int t = blockIdx.x * blockDim.x + threadIdx.x;
    int pair = t >> 6, lane = t & 63;
    if (2 * pair >= N) return;
    int node = 2 * pair + (lane >> 5);
    int g = (lane >> 4) & 1, d = lane & 15;
    bool valid = node < N;
    int2 se = valid ? row_se[node] : make_int2(0, 0);
    int start = se.x, end = se.y;
    GATHER_BODY(cur)
    if (valid && g == 0) {
        float w = dis[node];
        float inv = (w > 0.f) ? 1.0f / w : 0.f;
        size_t idx = (((size_t)node) << 5) + 2 * d;        // u32 units
        uint2 q1 = *(const uint2*)(e1b + idx);
        uint2 q2 = *(const uint2*)(cur + idx);
        float4 e0 = *(const float4*)(emb0 + 2 * idx);      // node*64 + 4d floats
        float4 r;
        r.x = 0.25f * (e0.x + (bf2f_lo(q1.x) + bf2f_lo(q2.x)) * inv + w * s0);
        r.y = 0.25f * (e0.y + (bf2f_hi(q1.x) + bf2f_hi(q2.x)) * inv + w * s1);
        r.z = 0.25f * (e0.z + (bf2f_lo(q1.y) + bf2f_lo(q2.y)) * inv + w * s2);
        r.w = 0.25f * (e0.w + (bf2f_hi(q1.y) + bf2f_hi(q2.y)) * inv + w * s3);
        *(float4*)(out + 2 * idx) = r;
    }
}

extern "C" void kernel_launch(void* const* d_in, const int* in_sizes, int n_in,
                              void* d_out, int out_size, void* d_ws, size_t ws_size,
                              hipStream_t stream) {
    const int*   edge  = (const int*)d_in[0];
    const float* emb_w = (const float*)d_in[1];
    const int E = in_sizes[0] / 2;
    const int N = in_sizes[1] / DIM;
    const int* src = edge;         // edge_index[0]
    const int* dst = edge + E;     // edge_index[1]

    const int NB  = (N + BN - 1) >> BSH;          // <= 256
    const int nCh = (E + CHUNK - 1) / CHUNK;
    const int CAP = (E / (NB > 0 ? NB : 1)) * 2;  // 2x mean bucket load (uniform dst)

    float* out_base = (float*)d_out;
    float* emb0_out = out_base;                       // first half of d_out
    float* acc      = out_base + (size_t)N * DIM;     // second half -> out

    // ws: [dis: N][row_se: N int2][cursor: 256][col: E]
    //     [zone: slab (NB*CAP u32) overlaid later by e0b|e1b (2 * N*64 u16)]
    float* dis       = (float*)d_ws;
    int2*  row_se    = (int2*)(dis + ((N + 1) & ~1));
    int*   cursor    = (int*)(row_se + N);
    int*   col       = cursor + 256;
    u32*   slab      = (u32*)(col + E);
    u16*   e0b       = (u16*)slab;                    // overlays slab (dead after c3)
    u16*   e1b       = e0b + (size_t)N * DIM;

    const int n4    = N * DIM / 4;
    const int BLK   = 256;
    const int g4    = (n4 + BLK - 1) / BLK;
    const int PAIRS = (N + 1) / 2;                    // 2 nodes per 64-lane wave
    const int gW    = (PAIRS * 64 + BLK - 1) / BLK;

    // --- CSR build ---
    hipMemsetAsync(cursor, 0, 256 * sizeof(int), stream);
    c1_scatter<<<nCh, 1024, 0, stream>>>(src, dst, cursor, slab, E, CAP);
    c3_build<<<NB, 1024, 0, stream>>>(slab, cursor, col, row_se, dis, N, CAP, NB);

    // Prescaled bf16 table + exact emb0 output (slab dead now).
    cvt_copy<<<g4, BLK, 0, stream>>>((const float4*)emb_w, dis,
                                     (ushort4*)e0b, (float4*)emb0_out, n4);

    // Layer 1: e1b = bf16(w*e1)
    gather_mid<<<gW, BLK, 0, stream>>>(row_se, col, dis, (const u32*)e0b, (u32*)e1b, N);
    // Layer 2: e2b = bf16(w*e2)  (e0b region reused as output)
    gather_mid<<<gW, BLK, 0, stream>>>(row_se, col, dis, (const u32*)e1b, (u32*)e0b, N);
    // Layer 3 + mean epilogue
    gather_final<<<gW, BLK, 0, stream>>>(row_se, col, dis, (const u32*)e0b, (const u32*)e1b,
                                         emb_w, acc, N);
}

// Round 13
// 245.210 us; speedup vs baseline: 1.9360x; 1.0093x over previous
//
#include <hip/hip_runtime.h>

// LightGCN forward on MI355X — slab-bucketed CSR build (register-staged, rank-trick)
// + paired-node dwordx2 gather with explicit 2-stage software pipeline.
// Inputs: d_in[0] = edge_index int32 [2, E]; d_in[1] = emb_weight f32 [N, 64].
// Output: d_out = [emb0 (N*64) | out (N*64)] f32, out = mean(emb0..emb3).
// Assumes N <= 131072 (<=256 buckets). Here N=120000, E=2M, dst ~uniform.
//
// R1: LDS-scatter accum = 727 µs/layer — reverted. R10: global-atomic build
//     REGRESSED (sub-line stores = full-line writes; atomic-return chains).
// R2: paired-node dwordx2 gather 53.3 -> 47.6 µs. R4/R7: pipeline + uint4 col
//     ~null. Gather FETCH 137 MB = COMPULSORY floor (8 XCDs x 15.4 MB table +
//     col) at ~2.9 TB/s random-access fabric rate — structural.
// R5: 32-B quartered table REGRESSED (line over-fetch). Rows stay >= 128 B.
// R6: fusing cvt into c3 raced the e0b/slab overlay — cvt stays separate.
// R11/R12: 1024-thr build + pass cuts: 262 -> 247.5. Build near latency floor.
// R13 (this round): (1) emb0_out copy moved from cvt (HBM-roofline-bound,
//     5.3 TB/s) into gather_final's epilogue which already loads those exact
//     float4s (gather is latency-bound at 45% fabric — write rides free);
//     (2) c1 CHUNK 4096->8192 (8 edges/thread, 43 KB LDS, 2 WGs/CU) to
//     amortize the 16-barrier scan chain over 2x edges.

#define DIM 64
#define BN 512          // nodes per bucket
#define BSH 9
#define CHUNK 8192      // edges per scatter workgroup (43 KB LDS, 2 WGs/CU)
#define EPT 20          // c3 max edges/thread: ceil(CAP/1024); CAP<=17020 here

typedef unsigned short u16;
typedef unsigned int u32;

static __device__ __forceinline__ float bf2f_lo(u32 p) { return __uint_as_float(p << 16); }
static __device__ __forceinline__ float bf2f_hi(u32 p) { return __uint_as_float(p & 0xffff0000u); }
static __device__ __forceinline__ u16 f2bf(float f) {   // round-to-nearest-even
    unsigned u = __float_as_uint(f);
    return (u16)((u + 0x7fffu + ((u >> 16) & 1u)) >> 16);
}
static __device__ __forceinline__ u32 pack2(float a, float b) {
    return (u32)f2bf(a) | ((u32)f2bf(b) << 16);
}

// Per-chunk LDS counting-sort by bucket; slab space reserved with one global
// atomicAdd per (chunk,bucket). Register-staged: each thread's 8 edges are
// loaded ONCE (two int4) before the first barrier; feed both hist & placement.
__global__ void __launch_bounds__(1024) c1_scatter(
        const int* __restrict__ src, const int* __restrict__ dst,
        int* __restrict__ cursor, u32* __restrict__ slab, int E, int CAP) {
    __shared__ u32 buf[CHUNK];
    __shared__ unsigned char bb[CHUNK];
    __shared__ int posb[256], startb[256], gbase[256];
    int w = blockIdx.x, tid = threadIdx.x;
    int lo = w * CHUNK, hi = min(lo + CHUNK, E);
    int i0 = lo + tid * 8;
    int nE = min(8, max(0, hi - i0));
    int sv[8], dv[8];
    if (nE == 8) {                                         // 32-B aligned (i0 % 8 == 0)
        int4 sa = *(const int4*)(src + i0), sb = *(const int4*)(src + i0 + 4);
        int4 da = *(const int4*)(dst + i0), db = *(const int4*)(dst + i0 + 4);
        sv[0] = sa.x; sv[1] = sa.y; sv[2] = sa.z; sv[3] = sa.w;
        sv[4] = sb.x; sv[5] = sb.y; sv[6] = sb.z; sv[7] = sb.w;
        dv[0] = da.x; dv[1] = da.y; dv[2] = da.z; dv[3] = da.w;
        dv[4] = db.x; dv[5] = db.y; dv[6] = db.z; dv[7] = db.w;
    } else {
#pragma unroll
        for (int k = 0; k < 8; ++k) {
            sv[k] = 0; dv[k] = 0;
            if (k < nE) { sv[k] = src[i0 + k]; dv[k] = dst[i0 + k]; }
        }
    }
    if (tid < 256) posb[tid] = 0;
    __syncthreads();
#pragma unroll
    for (int k = 0; k < 8; ++k)
        if (k < nE) atomicAdd(&posb[dv[k] >> BSH], 1);
    __syncthreads();
    int x = 0;
    if (tid < 256) {
        x = posb[tid];
        gbase[tid] = x ? atomicAdd(cursor + tid, x) : 0;   // slab reservation
    }
    __syncthreads();
    for (int off = 1; off < 256; off <<= 1) {              // in-place scan of posb
        int t = (tid >= off && tid < 256) ? posb[tid - off] : 0;
        __syncthreads();
        if (tid < 256) posb[tid] += t;
        __syncthreads();
    }
    if (tid < 256) startb[tid] = posb[tid] - x;
    __syncthreads();
    if (tid < 256) posb[tid] = startb[tid];                // placement cursor
    __syncthreads();
#pragma unroll
    for (int k = 0; k < 8; ++k)
        if (k < nE) {
            int d = dv[k], b = d >> BSH;
            int q = atomicAdd(&posb[b], 1);
            buf[q] = ((u32)sv[k] << BSH) | (u32)(d & (BN - 1));
            bb[q] = (unsigned char)b;
        }
    __syncthreads();
    int n = hi - lo;
    for (int q = tid; q < n; q += 1024) {                  // coalesced bucket-run writes
        int b = bb[q];
        slab[(size_t)b * CAP + gbase[b] + (q - startb[b])] = buf[q];
    }
}

// One WG per bucket. Rank trick: the histogram atomicAdd RETURNS each edge's
// rank within its node; (slab word, rank) stay in statically-indexed register
// arrays (EPT unrolled, predicated), so placement is one atomic-free pass:
// col[lo + base[node] + rank] = src. No second slab read. (R12-verified.)
__global__ void __launch_bounds__(1024) c3_build(
        const u32* __restrict__ slab, const int* __restrict__ cursor,
        int* __restrict__ col, int2* __restrict__ row_se, float* __restrict__ dis,
        int N, int CAP, int NB) {
    __shared__ int cur[BN];
    __shared__ int ps[BN];
    int b = blockIdx.x, tid = threadIdx.x;
    // exclusive prefix of bucket counts -> this bucket's lo (first 256 threads)
    int xc = (tid < NB) ? cursor[tid] : 0;
    if (tid < 256) ps[tid] = xc;
    __syncthreads();
    for (int off = 1; off < 256; off <<= 1) {
        int t = (tid >= off && tid < 256) ? ps[tid - off] : 0;
        __syncthreads();
        if (tid < 256) ps[tid] += t;
        __syncthreads();
    }
    int lo  = b ? ps[b - 1] : 0;
    int cnt = cursor[b];
    __syncthreads();

    int nodeBase = b << BSH;
    int nLoc = min(BN, N - nodeBase);
    const u32* sp = slab + (size_t)b * CAP;
    if (tid < BN) cur[tid] = 0;                            // node histogram
    __syncthreads();
    u32 ew[EPT];                                           // slab words (static idx)
    u32 rk[EPT];                                           // ranks from hist atomics
#pragma unroll
    for (int k = 0; k < EPT; ++k) {
        int i = tid + (k << 10);
        ew[k] = 0; rk[k] = 0;
        if (i < cnt) {
            u32 v = sp[i];
            ew[k] = v;
            rk[k] = atomicAdd(&cur[v & (BN - 1)], 1);
        }
    }
    __syncthreads();
    int c0 = (tid < BN) ? cur[tid] : 0;
    if (tid < BN) ps[tid] = c0;
    __syncthreads();
    for (int off = 1; off < BN; off <<= 1) {               // scan of node counts
        int t = (tid >= off && tid < BN) ? ps[tid - off] : 0;
        __syncthreads();
        if (tid < BN) ps[tid] += t;
        __syncthreads();
    }
    if (tid < BN) {
        int base = ps[tid] - c0;                           // exclusive
        cur[tid] = base;                                   // node base (no atomics now)
        if (tid < nLoc) {
            dis[nodeBase + tid] = c0 ? rsqrtf((float)c0) : 0.f;
            row_se[nodeBase + tid] = make_int2(lo + base, lo + base + c0);
        }
    }
    __syncthreads();
#pragma unroll
    for (int k = 0; k < EPT; ++k) {
        int i = tid + (k << 10);
        if (i < cnt) {
            u32 v = ew[k];
            col[lo + cur[v & (BN - 1)] + (int)rk[k]] = (int)(v >> BSH);
        }
    }
}

// e0b = bf16(dis * emb0) prescaled table ONLY (emb0_out copy moved into
// gather_final, which already loads those float4s — rides free on its BW slack).
// SEPARATE kernel (after c3_build retires) — slab/e0b overlay only then safe (R6).
__global__ void cvt_copy(const float4* __restrict__ emb, const float* __restrict__ dis,
                         ushort4* __restrict__ e0b, int n4) {
    int i = blockIdx.x * blockDim.x + threadIdx.x;
    if (i < n4) {
        float4 v = emb[i];
        float w = dis[i >> 4];
        ushort4 o;
        o.x = f2bf(w * v.x); o.y = f2bf(w * v.y);
        o.z = f2bf(w * v.z); o.w = f2bf(w * v.w);
        e0b[i] = o;
    }
}

#define ACC4(P) { s0 += bf2f_lo((P).x); s1 += bf2f_hi((P).x);                  \
                  s2 += bf2f_lo((P).y); s3 += bf2f_hi((P).y); }

// Paired-node gather body (R4-verified). Wave = 2 nodes (lane halves); subgroup
// g=(lane>>4)&1 handles edges j+2k+g; lane d=(lane&15) loads dwordx2 = dims
// 4d..4d+3 of the 128-B prescaled row. 2-stage rotation: issue round r's
// col+rows before accumulating round r-1. Tail: ONE predicated round, index
// clamped to end-1, loaded words zero-masked. Reduce across g via shfl_xor(16).
#define GATHER_BODY(CURTAB)                                                    \
    float s0 = 0.f, s1 = 0.f, s2 = 0.f, s3 = 0.f;                              \
    {                                                                          \
        int nfull = (end - start) >> 3;                                        \
        uint2 p0, p1, p2, p3;                                                  \
        if (nfull > 0) {                                                       \
            int j = start;                                                     \
            int a0 = col[j + g],     a1 = col[j + 2 + g];                      \
            int a2 = col[j + 4 + g], a3 = col[j + 6 + g];                      \
            p0 = *(const uint2*)((CURTAB) + (((size_t)a0) << 5) + 2 * d);      \
            p1 = *(const uint2*)((CURTAB) + (((size_t)a1) << 5) + 2 * d);      \
            p2 = *(const uint2*)((CURTAB) + (((size_t)a2) << 5) + 2 * d);      \
            p3 = *(const uint2*)((CURTAB) + (((size_t)a3) << 5) + 2 * d);      \
        }                                                                      \
        for (int r = 1; r < nfull; ++r) {                                      \
            int jn = start + 8 * r;                                            \
            int b0 = col[jn + g],     b1 = col[jn + 2 + g];                    \
            int b2 = col[jn + 4 + g], b3 = col[jn + 6 + g];                    \
            uint2 q0 = *(const uint2*)((CURTAB) + (((size_t)b0) << 5) + 2 * d);\
            uint2 q1 = *(const uint2*)((CURTAB) + (((size_t)b1) << 5) + 2 * d);\
            uint2 q2 = *(const uint2*)((CURTAB) + (((size_t)b2) << 5) + 2 * d);\
            uint2 q3 = *(const uint2*)((CURTAB) + (((size_t)b3) << 5) + 2 * d);\
            ACC4(p0) ACC4(p1) ACC4(p2) ACC4(p3)                                \
            p0 = q0; p1 = q1; p2 = q2; p3 = q3;                                \
        }                                                                      \
        if (nfull > 0) { ACC4(p0) ACC4(p1) ACC4(p2) ACC4(p3) }                 \
        int jt = start + 8 * nfull;                                            \
        if (jt < end) {                                                        \
            int endm1 = end - 1;                                               \
            _Pragma("unroll")                                                  \
            for (int k = 0; k < 4; ++k) {                                      \
                int e = jt + 2 * k + g;                                        \
                int c = col[min(e, endm1)];                                    \
                uint2 p = *(const uint2*)((CURTAB) + (((size_t)c) << 5) + 2 * d); \
                if (e >= end) { p.x = 0; p.y = 0; }                            \
                ACC4(p)                                                        \
            }                                                                  \
        }                                                                      \
    }                                                                          \
    s0 += __shfl_xor(s0, 16); s1 += __shfl_xor(s1, 16);                        \
    s2 += __shfl_xor(s2, 16); s3 += __shfl_xor(s3, 16);

// cur is the PRESCALED table (dis ⊙ e). Writes next = bf16(w*e) only.
__global__ void __launch_bounds__(256) gather_mid(
        const int2* __restrict__ row_se, const int* __restrict__ col,
        const float* __restrict__ dis, const u32* __restrict__ cur,
        u32* __restrict__ next, int N) {
    int t = blockIdx.x * blockDim.x + threadIdx.x;
    int pair = t >> 6, lane = t & 63;
    if (2 * pair >= N) return;
    int node = 2 * pair + (lane >> 5);
    int g = (lane >> 4) & 1, d = lane & 15;
    bool valid = node < N;
    int2 se = valid ? row_se[node] : make_int2(0, 0);
    int start = se.x, end = se.y;
    GATHER_BODY(cur)
    if (valid && g == 0) {
        float w = dis[node], ww = w * w;
        uint2 o;
        o.x = pack2(ww * s0, ww * s1);
        o.y = pack2(ww * s2, ww * s3);
        *(uint2*)(next + (((size_t)node) << 5) + 2 * d) = o;
    }
}

// Final gather (layer 3) fused with the mean epilogue AND the emb0 copy:
// emb0_out = e0 (exact f32); out = 0.25*(e0 + (e1b+e2b)/w + w*sum).
__global__ void __launch_bounds__(256) gather_final(
        const int2* __restrict__ row_se, const int* __restrict__ col,
        const float* __restrict__ dis, const u32* __restrict__ cur /* e2b */,
        const u32* __restrict__ e1b, const float* __restrict__ emb0,
        float* __restrict__ emb0_out, float* __restrict__ out, int N) {
    int t = blockIdx.x * blockDim.x + threadIdx.x;
    int pair = t >> 6, lane = t & 63;
    if (2 * pair >= N) return;
    int node = 2 * pair + (lane >> 5);
    int g = (lane >> 4) & 1, d = lane & 15;
    bool valid = node < N;
    int2 se = valid ? row_se[node] : make_int2(0, 0);
    int start = se.x, end = se.y;
    GATHER_BODY(cur)
    if (valid && g == 0) {
        float w = dis[node];
        float inv = (w > 0.f) ? 1.0f / w : 0.f;
        size_t idx = (((size_t)node) << 5) + 2 * d;        // u32 units
        uint2 q1 = *(const uint2*)(e1b + idx);
        uint2 q2 = *(const uint2*)(cur + idx);
        float4 e0 = *(const float4*)(emb0 + 2 * idx);      // node*64 + 4d floats
        *(float4*)(emb0_out + 2 * idx) = e0;               // exact emb0 output
        float4 r;
        r.x = 0.25f * (e0.x + (bf2f_lo(q1.x) + bf2f_lo(q2.x)) * inv + w * s0);
        r.y = 0.25f * (e0.y + (bf2f_hi(q1.x) + bf2f_hi(q2.x)) * inv + w * s1);
        r.z = 0.25f * (e0.z + (bf2f_lo(q1.y) + bf2f_lo(q2.y)) * inv + w * s2);
        r.w = 0.25f * (e0.w + (bf2f_hi(q1.y) + bf2f_hi(q2.y)) * inv + w * s3);
        *(float4*)(out + 2 * idx) = r;
    }
}

extern "C" void kernel_launch(void* const* d_in, const int* in_sizes, int n_in,
                              void* d_out, int out_size, void* d_ws, size_t ws_size,
                              hipStream_t stream) {
    const int*   edge  = (const int*)d_in[0];
    const float* emb_w = (const float*)d_in[1];
    const int E = in_sizes[0] / 2;
    const int N = in_sizes[1] / DIM;
    const int* src = edge;         // edge_index[0]
    const int* dst = edge + E;     // edge_index[1]

    const int NB  = (N + BN - 1) >> BSH;          // <= 256
    const int nCh = (E + CHUNK - 1) / CHUNK;
    const int CAP = (E / (NB > 0 ? NB : 1)) * 2;  // 2x mean bucket load (uniform dst)

    float* out_base = (float*)d_out;
    float* emb0_out = out_base;                       // first half of d_out
    float* acc      = out_base + (size_t)N * DIM;     // second half -> out

    // ws: [dis: N][row_se: N int2][cursor: 256][col: E]
    //     [zone: slab (NB*CAP u32) overlaid later by e0b|e1b (2 * N*64 u16)]
    float* dis       = (float*)d_ws;
    int2*  row_se    = (int2*)(dis + ((N + 1) & ~1));
    int*   cursor    = (int*)(row_se + N);
    int*   col       = cursor + 256;
    u32*   slab      = (u32*)(col + E);
    u16*   e0b       = (u16*)slab;                    // overlays slab (dead after c3)
    u16*   e1b       = e0b + (size_t)N * DIM;

    const int n4    = N * DIM / 4;
    const int BLK   = 256;
    const int g4    = (n4 + BLK - 1) / BLK;
    const int PAIRS = (N + 1) / 2;                    // 2 nodes per 64-lane wave
    const int gW    = (PAIRS * 64 + BLK - 1) / BLK;

    // --- CSR build ---
    hipMemsetAsync(cursor, 0, 256 * sizeof(int), stream);
    c1_scatter<<<nCh, 1024, 0, stream>>>(src, dst, cursor, slab, E, CAP);
    c3_build<<<NB, 1024, 0, stream>>>(slab, cursor, col, row_se, dis, N, CAP, NB);

    // Prescaled bf16 table (slab dead now).
    cvt_copy<<<g4, BLK, 0, stream>>>((const float4*)emb_w, dis, (ushort4*)e0b, n4);

    // Layer 1: e1b = bf16(w*e1)
    gather_mid<<<gW, BLK, 0, stream>>>(row_se, col, dis, (const u32*)e0b, (u32*)e1b, N);
    // Layer 2: e2b = bf16(w*e2)  (e0b region reused as output)
    gather_mid<<<gW, BLK, 0, stream>>>(row_se, col, dis, (const u32*)e1b, (u32*)e0b, N);
    // Layer 3 + mean epilogue + emb0 copy
    gather_final<<<gW, BLK, 0, stream>>>(row_se, col, dis, (const u32*)e0b, (const u32*)e1b,
                                         emb_w, emb0_out, acc, N);
}